// Round 2
// baseline (1776.168 us; speedup 1.0000x reference)
//
#include <hip/hip_runtime.h>
#include <hip/hip_bf16.h>
#include <cstdint>
#include <cstddef>

#define AA 96
#define DD 96
#define HH 96
#define WWI 96
#define PP (HH*WWI)   // 9216
#define NPRIM 5
#define NITER 10
#define IMG (HH*WWI)  // 9216 per channel

// ---------------- init: copy dual+primal into ws ping-pong buffers ----------------
__global__ void k_init(const float* __restrict__ dual, const float* __restrict__ primal,
                       float* __restrict__ dualA, float* __restrict__ primA){
  int i = blockIdx.x*blockDim.x + threadIdx.x;
  if (i < PP) dualA[i] = dual[i];
  if (i < NPRIM*PP) primA[i] = primal[i];
}

// ---------------- ev1 partial: grid (96 a, 16 chunks), block 256 ----------------
// ev1[a,x] = sum_p Snorm[a,0,p,x] * img[p],  img[p] = primal[ch1][h,w], p = w*96+h
__global__ void k_ev1_partial(const float* __restrict__ Snorm, const float* __restrict__ prim,
                              float* __restrict__ part){
  const int a = blockIdx.x, c = blockIdx.y;
  const int p0 = c*576;
  const int tid = threadIdx.x;
  __shared__ float img[576];
  __shared__ float4 red[240];
  const float* prim1 = prim + IMG; // channel 1
  for (int idx = tid; idx < 576; idx += 256){
    int p = p0 + idx;
    int h = p % 96, w = p / 96;
    img[idx] = prim1[h*96 + w];
  }
  __syncthreads();
  if (tid < 240){
    const int xg = tid % 24, pr = tid / 24;
    float4 acc = make_float4(0.f,0.f,0.f,0.f);
    const float* base = Snorm + ((size_t)a*PP + p0)*96 + 4*xg;
    for (int pi = pr; pi < 576; pi += 10){
      const float4 s = *reinterpret_cast<const float4*>(base + (size_t)pi*96);
      const float im = img[pi];
      acc.x += im*s.x; acc.y += im*s.y; acc.z += im*s.z; acc.w += im*s.w;
    }
    red[tid] = acc;
  }
  __syncthreads();
  if (tid < 24){
    float4 r = red[tid];
    #pragma unroll
    for (int q = 1; q < 10; ++q){
      float4 o = red[tid + 24*q];
      r.x += o.x; r.y += o.y; r.z += o.z; r.w += o.w;
    }
    *reinterpret_cast<float4*>(&part[((size_t)a*16 + c)*96 + 4*tid]) = r;
  }
}

// ---------------- ev1 reduce over 16 chunks ----------------
__global__ void k_ev1_reduce(const float* __restrict__ part, float* __restrict__ ev1){
  int t = blockIdx.x*blockDim.x + threadIdx.x;
  if (t >= PP) return;
  int a = t / 96, x = t % 96;
  float s = 0.f;
  #pragma unroll
  for (int c = 0; c < 16; ++c) s += part[((size_t)a*16 + c)*96 + x];
  ev1[t] = s;
}

// ---------------- back projection: grid 1152 (8 p-rows each), block 192 ----------------
// bp[p] = sum_{a,x} S[a,0,p,x]*dual[a,x]; ev2 image [h][w] = bp[w*96+h]
__global__ void k_bp(const float* __restrict__ S, const float* __restrict__ dual,
                     float* __restrict__ ev2){
  __shared__ float d2[PP];
  __shared__ float red[192];
  const int tid = threadIdx.x;
  for (int i = tid; i < PP; i += 192) d2[i] = dual[i];
  __syncthreads();
  const int p0 = blockIdx.x * 8;
  const int xg = tid % 24, pr = tid / 24;
  const int p = p0 + pr;
  float acc = 0.f;
  const float* base = S + (size_t)p*96 + 4*xg;
  #pragma unroll 4
  for (int a = 0; a < 96; ++a){
    const float4 s  = *reinterpret_cast<const float4*>(base + (size_t)a*PP*96);
    const float4 dv = *reinterpret_cast<const float4*>(&d2[a*96 + 4*xg]);
    acc += s.x*dv.x + s.y*dv.y + s.z*dv.z + s.w*dv.w;
  }
  red[tid] = acc;
  __syncthreads();
  if (tid < 8){
    float s = 0.f;
    #pragma unroll
    for (int j = 0; j < 24; ++j) s += red[tid*24 + j];
    int pp = p0 + tid;
    int h = pp % 96, w = pp / 96;
    ev2[h*96 + w] = s;
  }
}

// ---------------- fused conv1+PReLU+conv2+PReLU+conv3+residual block ----------------
// 6x6 output tile per block, grid 16x16, block 256. LDS phases overlaid to stay <64KB.
// NOTE: each conv layer zero-pads its OWN input at the image boundary ('SAME'),
// so intermediate (conv1/conv2) values at out-of-image positions must be ZERO.
template<int CIN, int COUT>
__global__ __launch_bounds__(256) void k_conv_block(
    const float* __restrict__ inA, int nA, const float* __restrict__ inB, int nB,
    const float* __restrict__ inC,
    const float* __restrict__ W1, const float* __restrict__ B1, const float* __restrict__ A1,
    const float* __restrict__ W2, const float* __restrict__ B2, const float* __restrict__ A2,
    const float* __restrict__ W3, const float* __restrict__ B3,
    float* __restrict__ out)
{
  constexpr int C1F  = 32*10*12;   // conv1 out tile [32][10][12-padded]
  constexpr int C2F  = 32*8*9;     // conv2 out tile [32][8][9-padded]
  constexpr int XINF = CIN*144;    // input tile [CIN][12][12]
  constexpr int W1F  = 32*CIN*9;
  constexpr int W2F  = 288*32;     // w2 transposed [ci*9+k][och]
  constexpr int W3F  = COUT*32*9;
  constexpr int OV1  = (XINF+W1F > W2F) ? XINF+W1F : W2F;
  constexpr int OVLF = (OV1 > W3F) ? OV1 : W3F;

  __shared__ float c1s[C1F];
  __shared__ float c2s[C2F];
  __shared__ float bias1[32], bias2[32], bias3[COUT], alph[2];
  __shared__ float ovl[OVLF];

  const int tid = threadIdx.x;
  const int x0 = blockIdx.x * 6, y0 = blockIdx.y * 6;

  float* xin = ovl;            // [CIN][12][12]
  float* w1s = ovl + XINF;

  // ---- load input tile (zero-padded) + w1 + biases/alphas ----
  for (int i = tid; i < XINF; i += 256){
    int ch = i / 144, r = (i % 144) / 12, cc = i % 12;
    int gy = y0 - 3 + r, gx = x0 - 3 + cc;
    float v = 0.f;
    if (gy >= 0 && gy < 96 && gx >= 0 && gx < 96){
      const float* src = (ch < nA) ? (inA + (size_t)ch*IMG)
                       : (ch < nA+nB) ? (inB + (size_t)(ch-nA)*IMG)
                       : (inC + (size_t)(ch-nA-nB)*IMG);
      v = src[gy*96 + gx];
    }
    xin[i] = v;
  }
  for (int i = tid; i < W1F; i += 256) w1s[i] = W1[i];
  if (tid < 32) bias1[tid] = B1[tid];
  else if (tid < 64) bias2[tid-32] = B2[tid-32];
  else if (tid < 64+COUT) bias3[tid-64] = B3[tid-64];
  else if (tid == 96) alph[0] = A1[0];
  else if (tid == 97) alph[1] = A2[0];
  __syncthreads();

  // ---- conv1 (CIN -> 32) + PReLU ----
  {
    const int och = tid & 31, t = tid >> 5;
    const float al = alph[0];
    for (int r = t; r < 10; r += 8){
      const int gy = y0 - 2 + r;
      float acc[10];
      #pragma unroll
      for (int cc = 0; cc < 10; ++cc) acc[cc] = bias1[och];
      #pragma unroll
      for (int ci = 0; ci < CIN; ++ci){
        float xr[3][12];
        #pragma unroll
        for (int ky = 0; ky < 3; ++ky){
          #pragma unroll
          for (int j = 0; j < 3; ++j){
            float4 q = *reinterpret_cast<const float4*>(&xin[ci*144 + (r+ky)*12 + 4*j]);
            xr[ky][4*j+0]=q.x; xr[ky][4*j+1]=q.y; xr[ky][4*j+2]=q.z; xr[ky][4*j+3]=q.w;
          }
        }
        float wv[9];
        #pragma unroll
        for (int kk = 0; kk < 9; ++kk) wv[kk] = w1s[(och*CIN+ci)*9 + kk];
        #pragma unroll
        for (int ky = 0; ky < 3; ++ky)
          #pragma unroll
          for (int kx = 0; kx < 3; ++kx)
            #pragma unroll
            for (int cc = 0; cc < 10; ++cc)
              acc[cc] += xr[ky][cc+kx] * wv[ky*3+kx];
      }
      const bool yin = (gy >= 0 && gy < 96);
      #pragma unroll
      for (int cc = 0; cc < 10; ++cc){
        const int gx = x0 - 2 + cc;
        float v = acc[cc];
        v = (v >= 0.f) ? v : al*v;
        // zero-pad semantics: out-of-image intermediate values are ZERO
        const bool in = yin && (gx >= 0 && gx < 96);
        c1s[(och*10 + r)*12 + cc] = in ? v : 0.f;
      }
    }
  }
  // ---- pull residual into regs before xin is overlaid ----
  float resv = 0.f;
  {
    int sp = tid % 36, och = tid / 36;
    if (och < COUT){
      int ty = sp / 6, tx = sp % 6;
      resv = xin[och*144 + (ty+3)*12 + (tx+3)];
    }
  }
  __syncthreads();

  // ---- load w2 transposed into overlay ----
  float* w2t = ovl;
  for (int i = tid; i < W2F; i += 256){
    w2t[i] = W2[(size_t)(i & 31)*288 + (i >> 5)];
  }
  __syncthreads();

  // ---- conv2 (32 -> 32) + PReLU ----
  {
    const int och = tid & 31, ty = tid >> 5;  // ty 0..7
    const int gy = y0 - 1 + ty;
    const float al = alph[1];
    float acc[8];
    #pragma unroll
    for (int cc = 0; cc < 8; ++cc) acc[cc] = bias2[och];
    for (int ci = 0; ci < 32; ++ci){
      float cr[3][12];
      #pragma unroll
      for (int ky = 0; ky < 3; ++ky){
        #pragma unroll
        for (int j = 0; j < 3; ++j){
          float4 q = *reinterpret_cast<const float4*>(&c1s[(ci*10 + ty+ky)*12 + 4*j]);
          cr[ky][4*j+0]=q.x; cr[ky][4*j+1]=q.y; cr[ky][4*j+2]=q.z; cr[ky][4*j+3]=q.w;
        }
      }
      float wv[9];
      #pragma unroll
      for (int kk = 0; kk < 9; ++kk) wv[kk] = w2t[(ci*9+kk)*32 + och];
      #pragma unroll
      for (int ky = 0; ky < 3; ++ky)
        #pragma unroll
        for (int kx = 0; kx < 3; ++kx)
          #pragma unroll
          for (int cc = 0; cc < 8; ++cc)
            acc[cc] += cr[ky][cc+kx] * wv[ky*3+kx];
    }
    const bool yin = (gy >= 0 && gy < 96);
    #pragma unroll
    for (int cc = 0; cc < 8; ++cc){
      const int gx = x0 - 1 + cc;
      float v = acc[cc];
      v = (v >= 0.f) ? v : al*v;
      const bool in = yin && (gx >= 0 && gx < 96);
      c2s[(och*8 + ty)*9 + cc] = in ? v : 0.f;
    }
  }
  __syncthreads();

  // ---- load w3 into overlay ----
  float* w3s = ovl;
  for (int i = tid; i < W3F; i += 256) w3s[i] = W3[i];
  __syncthreads();

  // ---- conv3 (32 -> COUT) + bias + residual ----
  {
    int sp = tid % 36, och = tid / 36;
    if (och < COUT){
      int ty = sp / 6, tx = sp % 6;
      float acc = bias3[och];
      for (int ci = 0; ci < 32; ++ci){
        #pragma unroll
        for (int ky = 0; ky < 3; ++ky)
          #pragma unroll
          for (int kx = 0; kx < 3; ++kx)
            acc += c2s[(ci*8 + ty+ky)*9 + (tx+kx)] * w3s[(och*32+ci)*9 + ky*3+kx];
      }
      out[(size_t)och*IMG + (y0+ty)*96 + (x0+tx)] = resv + acc;
    }
  }
}

// ---------------- extract primal channel 0 ----------------
__global__ void k_extract(const float* __restrict__ prim, float* __restrict__ out){
  int i = blockIdx.x*blockDim.x + threadIdx.x;
  if (i < PP) out[i] = prim[i];
}

extern "C" void kernel_launch(void* const* d_in, const int* in_sizes, int n_in,
                              void* d_out, int out_size, void* d_ws, size_t ws_size,
                              hipStream_t stream){
  (void)in_sizes; (void)n_in; (void)out_size; (void)ws_size;
  const float* dual   = (const float*)d_in[0];
  const float* primal = (const float*)d_in[1];
  const float* proj   = (const float*)d_in[2];
  const float* S      = (const float*)d_in[3];
  const float* Snorm  = (const float*)d_in[4];
  const float* dW1 = (const float*)d_in[5];
  const float* db1 = (const float*)d_in[6];
  const float* da1 = (const float*)d_in[7];
  const float* dW2 = (const float*)d_in[8];
  const float* db2 = (const float*)d_in[9];
  const float* da2 = (const float*)d_in[10];
  const float* dW3 = (const float*)d_in[11];
  const float* db3 = (const float*)d_in[12];
  const float* pW1 = (const float*)d_in[13];
  const float* pb1 = (const float*)d_in[14];
  const float* pa1 = (const float*)d_in[15];
  const float* pW2 = (const float*)d_in[16];
  const float* pb2 = (const float*)d_in[17];
  const float* pa2 = (const float*)d_in[18];
  const float* pW3 = (const float*)d_in[19];
  const float* pb3 = (const float*)d_in[20];

  float* ws = (float*)d_ws;
  float* dualA = ws;  ws += PP;
  float* dualB = ws;  ws += PP;
  float* primA = ws;  ws += NPRIM*PP;
  float* primB = ws;  ws += NPRIM*PP;
  float* ev1   = ws;  ws += PP;
  float* ev2   = ws;  ws += PP;
  float* part  = ws;  ws += 16*PP;

  k_init<<<dim3((NPRIM*PP + 255)/256), 256, 0, stream>>>(dual, primal, dualA, primA);

  for (int k = 0; k < NITER; ++k){
    float* dcur = (k & 1) ? dualB : dualA;
    float* dnxt = (k & 1) ? dualA : dualB;
    float* pcur = (k & 1) ? primB : primA;
    float* pnxt = (k & 1) ? primA : primB;

    k_ev1_partial<<<dim3(96,16), 256, 0, stream>>>(Snorm, pcur, part);
    k_ev1_reduce<<<36, 256, 0, stream>>>(part, ev1);
    k_conv_block<3,1><<<dim3(16,16), 256, 0, stream>>>(
        dcur, 1, ev1, 1, proj,
        dW1 + (size_t)k*32*3*9, db1 + (size_t)k*32, da1 + k,
        dW2 + (size_t)k*32*32*9, db2 + (size_t)k*32, da2 + k,
        dW3 + (size_t)k*1*32*9, db3 + (size_t)k*1, dnxt);
    k_bp<<<1152, 192, 0, stream>>>(S, dnxt, ev2);
    k_conv_block<6,5><<<dim3(16,16), 256, 0, stream>>>(
        pcur, 5, ev2, 1, ev2,
        pW1 + (size_t)k*32*6*9, pb1 + (size_t)k*32, pa1 + k,
        pW2 + (size_t)k*32*32*9, pb2 + (size_t)k*32, pa2 + k,
        pW3 + (size_t)k*5*32*9, pb3 + (size_t)k*5, pnxt);
  }

  k_extract<<<36, 256, 0, stream>>>(primA, (float*)d_out);
}

// Round 3
// 1262.849 us; speedup vs baseline: 1.4065x; 1.4065x over previous
//
#include <hip/hip_runtime.h>
#include <hip/hip_fp16.h>
#include <cstdint>
#include <cstddef>

#define PP 9216
#define NPRIM 5
#define NITER 10
#define IMG 9216

union H8 { float4 f4; __half h[8]; };

// ---------------- ev1 partial: grid (96 a, 16 chunks), block 256 ----------------
// ev1[a,x] = sum_p Snorm[a,0,p,x] * img[p],  img[p] = primal[ch1][h,w], p = w*96+h
// MODE 0: pure fp32 (fallback, no ws for fp16)
// MODE 1: read fp32, round via fp16, write fp16 copy to S16
// MODE 2: read fp16 copy
template<int MODE>
__global__ __launch_bounds__(256) void k_ev1(const float* __restrict__ Sf,
                                             __half* __restrict__ S16,
                                             const float* __restrict__ prim,
                                             float* __restrict__ part){
  const int a = blockIdx.x, c = blockIdx.y;
  const int p0 = c*576;
  const int tid = threadIdx.x;
  __shared__ float img[576];
  __shared__ float red[240][8];
  const float* prim1 = prim + IMG; // channel 1
  for (int idx = tid; idx < 576; idx += 256){
    int p = p0 + idx;
    int h = p % 96, w = p / 96;
    img[idx] = prim1[h*96 + w];
  }
  __syncthreads();
  if (tid < 240){
    const int xg = tid % 12, pr = tid / 12;   // xg: 12 x 8 halves = 96, pr: 0..19
    float acc[8];
    #pragma unroll
    for (int j = 0; j < 8; ++j) acc[j] = 0.f;
    const size_t base = ((size_t)a*PP + p0)*96 + 8*xg;
    for (int pi = pr; pi < 576; pi += 20){
      float s[8];
      if (MODE == 2){
        H8 u; u.f4 = *reinterpret_cast<const float4*>(S16 + base + (size_t)pi*96);
        #pragma unroll
        for (int j = 0; j < 8; ++j) s[j] = __half2float(u.h[j]);
      } else {
        const float4 q0 = *reinterpret_cast<const float4*>(Sf + base + (size_t)pi*96);
        const float4 q1 = *reinterpret_cast<const float4*>(Sf + base + (size_t)pi*96 + 4);
        float t[8] = {q0.x,q0.y,q0.z,q0.w,q1.x,q1.y,q1.z,q1.w};
        if (MODE == 1){
          H8 u;
          #pragma unroll
          for (int j = 0; j < 8; ++j){ u.h[j] = __float2half(t[j]); s[j] = __half2float(u.h[j]); }
          *reinterpret_cast<float4*>(S16 + base + (size_t)pi*96) = u.f4;
        } else {
          #pragma unroll
          for (int j = 0; j < 8; ++j) s[j] = t[j];
        }
      }
      const float im = img[pi];
      #pragma unroll
      for (int j = 0; j < 8; ++j) acc[j] += im*s[j];
    }
    #pragma unroll
    for (int j = 0; j < 8; ++j) red[tid][j] = acc[j];
  }
  __syncthreads();
  if (tid < 12){
    float r[8];
    #pragma unroll
    for (int j = 0; j < 8; ++j) r[j] = red[tid][j];
    for (int q = 1; q < 20; ++q)
      #pragma unroll
      for (int j = 0; j < 8; ++j) r[j] += red[tid + 12*q][j];
    float* dst = &part[((size_t)a*16 + c)*96 + 8*tid];
    #pragma unroll
    for (int j = 0; j < 8; ++j) dst[j] = r[j];
  }
}

// ---------------- back projection: grid 576 (16 p-rows each), block 192 ----------------
// bp[p] = sum_{a,x} S[a,0,p,x]*dual[a,x]; ev2 image [h][w] = bp[w*96+h]
template<int MODE>
__global__ __launch_bounds__(192) void k_bp(const float* __restrict__ Sf,
                                            __half* __restrict__ S16,
                                            const float* __restrict__ dual,
                                            float* __restrict__ ev2){
  __shared__ float d2[PP];
  __shared__ float red[192];
  const int tid = threadIdx.x;
  for (int i = tid; i < PP; i += 192) d2[i] = dual[i];
  __syncthreads();
  const int p0 = blockIdx.x * 16;
  const int xg = tid % 12, pr = tid / 12;   // xg: 12 x 8 halves = 96, pr: 0..15
  const int p = p0 + pr;
  float acc = 0.f;
  const size_t base = (size_t)p*96 + 8*xg;
  for (int a = 0; a < 96; ++a){
    float s[8];
    if (MODE == 2){
      H8 u; u.f4 = *reinterpret_cast<const float4*>(S16 + base + (size_t)a*PP*96);
      #pragma unroll
      for (int j = 0; j < 8; ++j) s[j] = __half2float(u.h[j]);
    } else {
      const float4 q0 = *reinterpret_cast<const float4*>(Sf + base + (size_t)a*PP*96);
      const float4 q1 = *reinterpret_cast<const float4*>(Sf + base + (size_t)a*PP*96 + 4);
      float t[8] = {q0.x,q0.y,q0.z,q0.w,q1.x,q1.y,q1.z,q1.w};
      if (MODE == 1){
        H8 u;
        #pragma unroll
        for (int j = 0; j < 8; ++j){ u.h[j] = __float2half(t[j]); s[j] = __half2float(u.h[j]); }
        *reinterpret_cast<float4*>(S16 + base + (size_t)a*PP*96) = u.f4;
      } else {
        #pragma unroll
        for (int j = 0; j < 8; ++j) s[j] = t[j];
      }
    }
    const float* dp = &d2[a*96 + 8*xg];
    #pragma unroll
    for (int j = 0; j < 8; ++j) acc += s[j]*dp[j];
  }
  red[tid] = acc;
  __syncthreads();
  if (tid < 16){
    float s = 0.f;
    #pragma unroll
    for (int j = 0; j < 12; ++j) s += red[tid*12 + j];
    int pp = p0 + tid;
    int h = pp % 96, w = pp / 96;
    ev2[h*96 + w] = s;
  }
}

// ---------------- fused conv1+PReLU+conv2+PReLU+conv3+residual block ----------------
// 6x6 output tile per block, grid 16x16, block 256. LDS phases overlaid to stay <64KB.
// Each conv layer zero-pads its OWN input ('SAME'): intermediate values at
// out-of-image positions are forced to ZERO.
// REDB: inB is the 16-chunk partial buffer; the loader sums the chunks (fused ev1 reduce).
// out2: if non-null, conv3 channel 0 is also written there (fused final extract).
template<int CIN, int COUT, bool REDB>
__global__ __launch_bounds__(256) void k_conv_block(
    const float* __restrict__ inA, int nA, const float* __restrict__ inB, int nB,
    const float* __restrict__ inC,
    const float* __restrict__ W1, const float* __restrict__ B1, const float* __restrict__ A1,
    const float* __restrict__ W2, const float* __restrict__ B2, const float* __restrict__ A2,
    const float* __restrict__ W3, const float* __restrict__ B3,
    float* __restrict__ out, float* __restrict__ out2)
{
  constexpr int C1F  = 32*10*12;   // conv1 out tile [32][10][12-padded]
  constexpr int C2F  = 32*8*9;     // conv2 out tile [32][8][9-padded]
  constexpr int XINF = CIN*144;    // input tile [CIN][12][12]
  constexpr int W1F  = 32*CIN*9;
  constexpr int W2F  = 288*32;     // w2 transposed [ci*9+k][och]
  constexpr int W3F  = COUT*32*9;
  constexpr int OV1  = (XINF+W1F > W2F) ? XINF+W1F : W2F;
  constexpr int OVLF = (OV1 > W3F) ? OV1 : W3F;

  __shared__ float c1s[C1F];
  __shared__ float c2s[C2F];
  __shared__ float bias1[32], bias2[32], bias3[COUT], alph[2];
  __shared__ float ovl[OVLF];

  const int tid = threadIdx.x;
  const int x0 = blockIdx.x * 6, y0 = blockIdx.y * 6;

  float* xin = ovl;            // [CIN][12][12]
  float* w1s = ovl + XINF;

  // ---- load input tile (zero-padded) + w1 + biases/alphas ----
  for (int i = tid; i < XINF; i += 256){
    int ch = i / 144, r = (i % 144) / 12, cc = i % 12;
    int gy = y0 - 3 + r, gx = x0 - 3 + cc;
    float v = 0.f;
    if (gy >= 0 && gy < 96 && gx >= 0 && gx < 96){
      if (REDB && ch >= nA && ch < nA + nB){
        float s = 0.f;
        #pragma unroll
        for (int cch = 0; cch < 16; ++cch) s += inB[((size_t)gy*16 + cch)*96 + gx];
        v = s;
      } else {
        const float* src = (ch < nA) ? (inA + (size_t)ch*IMG)
                         : (ch < nA+nB) ? (inB + (size_t)(ch-nA)*IMG)
                         : (inC + (size_t)(ch-nA-nB)*IMG);
        v = src[gy*96 + gx];
      }
    }
    xin[i] = v;
  }
  for (int i = tid; i < W1F; i += 256) w1s[i] = W1[i];
  if (tid < 32) bias1[tid] = B1[tid];
  else if (tid < 64) bias2[tid-32] = B2[tid-32];
  else if (tid < 64+COUT) bias3[tid-64] = B3[tid-64];
  else if (tid == 96) alph[0] = A1[0];
  else if (tid == 97) alph[1] = A2[0];
  __syncthreads();

  // ---- conv1 (CIN -> 32) + PReLU ----
  {
    const int och = tid & 31, t = tid >> 5;
    const float al = alph[0];
    for (int r = t; r < 10; r += 8){
      const int gy = y0 - 2 + r;
      float acc[10];
      #pragma unroll
      for (int cc = 0; cc < 10; ++cc) acc[cc] = bias1[och];
      #pragma unroll
      for (int ci = 0; ci < CIN; ++ci){
        float xr[3][12];
        #pragma unroll
        for (int ky = 0; ky < 3; ++ky){
          #pragma unroll
          for (int j = 0; j < 3; ++j){
            float4 q = *reinterpret_cast<const float4*>(&xin[ci*144 + (r+ky)*12 + 4*j]);
            xr[ky][4*j+0]=q.x; xr[ky][4*j+1]=q.y; xr[ky][4*j+2]=q.z; xr[ky][4*j+3]=q.w;
          }
        }
        float wv[9];
        #pragma unroll
        for (int kk = 0; kk < 9; ++kk) wv[kk] = w1s[(och*CIN+ci)*9 + kk];
        #pragma unroll
        for (int ky = 0; ky < 3; ++ky)
          #pragma unroll
          for (int kx = 0; kx < 3; ++kx)
            #pragma unroll
            for (int cc = 0; cc < 10; ++cc)
              acc[cc] += xr[ky][cc+kx] * wv[ky*3+kx];
      }
      const bool yin = (gy >= 0 && gy < 96);
      #pragma unroll
      for (int cc = 0; cc < 10; ++cc){
        const int gx = x0 - 2 + cc;
        float v = acc[cc];
        v = (v >= 0.f) ? v : al*v;
        const bool in = yin && (gx >= 0 && gx < 96);
        c1s[(och*10 + r)*12 + cc] = in ? v : 0.f;
      }
    }
  }
  // ---- pull residual into regs before xin is overlaid ----
  float resv = 0.f;
  {
    int sp = tid % 36, och = tid / 36;
    if (och < COUT){
      int ty = sp / 6, tx = sp % 6;
      resv = xin[och*144 + (ty+3)*12 + (tx+3)];
    }
  }
  __syncthreads();

  // ---- load w2 transposed into overlay ----
  float* w2t = ovl;
  for (int i = tid; i < W2F; i += 256){
    w2t[i] = W2[(size_t)(i & 31)*288 + (i >> 5)];
  }
  __syncthreads();

  // ---- conv2 (32 -> 32) + PReLU ----
  {
    const int och = tid & 31, ty = tid >> 5;  // ty 0..7
    const int gy = y0 - 1 + ty;
    const float al = alph[1];
    float acc[8];
    #pragma unroll
    for (int cc = 0; cc < 8; ++cc) acc[cc] = bias2[och];
    for (int ci = 0; ci < 32; ++ci){
      float cr[3][12];
      #pragma unroll
      for (int ky = 0; ky < 3; ++ky){
        #pragma unroll
        for (int j = 0; j < 3; ++j){
          float4 q = *reinterpret_cast<const float4*>(&c1s[(ci*10 + ty+ky)*12 + 4*j]);
          cr[ky][4*j+0]=q.x; cr[ky][4*j+1]=q.y; cr[ky][4*j+2]=q.z; cr[ky][4*j+3]=q.w;
        }
      }
      float wv[9];
      #pragma unroll
      for (int kk = 0; kk < 9; ++kk) wv[kk] = w2t[(ci*9+kk)*32 + och];
      #pragma unroll
      for (int ky = 0; ky < 3; ++ky)
        #pragma unroll
        for (int kx = 0; kx < 3; ++kx)
          #pragma unroll
          for (int cc = 0; cc < 8; ++cc)
            acc[cc] += cr[ky][cc+kx] * wv[ky*3+kx];
    }
    const bool yin = (gy >= 0 && gy < 96);
    #pragma unroll
    for (int cc = 0; cc < 8; ++cc){
      const int gx = x0 - 1 + cc;
      float v = acc[cc];
      v = (v >= 0.f) ? v : al*v;
      const bool in = yin && (gx >= 0 && gx < 96);
      c2s[(och*8 + ty)*9 + cc] = in ? v : 0.f;
    }
  }
  __syncthreads();

  // ---- load w3 into overlay ----
  float* w3s = ovl;
  for (int i = tid; i < W3F; i += 256) w3s[i] = W3[i];
  __syncthreads();

  // ---- conv3 (32 -> COUT) + bias + residual ----
  {
    int sp = tid % 36, och = tid / 36;
    if (och < COUT){
      int ty = sp / 6, tx = sp % 6;
      float acc = bias3[och];
      for (int ci = 0; ci < 32; ++ci){
        #pragma unroll
        for (int ky = 0; ky < 3; ++ky)
          #pragma unroll
          for (int kx = 0; kx < 3; ++kx)
            acc += c2s[(ci*8 + ty+ky)*9 + (tx+kx)] * w3s[(och*32+ci)*9 + ky*3+kx];
      }
      const float vout = resv + acc;
      const int idx = (y0+ty)*96 + (x0+tx);
      out[(size_t)och*IMG + idx] = vout;
      if (out2 != nullptr && och == 0) out2[idx] = vout;
    }
  }
}

extern "C" void kernel_launch(void* const* d_in, const int* in_sizes, int n_in,
                              void* d_out, int out_size, void* d_ws, size_t ws_size,
                              hipStream_t stream){
  (void)in_sizes; (void)n_in; (void)out_size;
  const float* dual   = (const float*)d_in[0];
  const float* primal = (const float*)d_in[1];
  const float* proj   = (const float*)d_in[2];
  const float* S      = (const float*)d_in[3];
  const float* Snorm  = (const float*)d_in[4];
  const float* dW1 = (const float*)d_in[5];
  const float* db1 = (const float*)d_in[6];
  const float* da1 = (const float*)d_in[7];
  const float* dW2 = (const float*)d_in[8];
  const float* db2 = (const float*)d_in[9];
  const float* da2 = (const float*)d_in[10];
  const float* dW3 = (const float*)d_in[11];
  const float* db3 = (const float*)d_in[12];
  const float* pW1 = (const float*)d_in[13];
  const float* pb1 = (const float*)d_in[14];
  const float* pa1 = (const float*)d_in[15];
  const float* pW2 = (const float*)d_in[16];
  const float* pb2 = (const float*)d_in[17];
  const float* pa2 = (const float*)d_in[18];
  const float* pW3 = (const float*)d_in[19];
  const float* pb3 = (const float*)d_in[20];

  const size_t S16E = (size_t)96*PP*96;                 // 84,934,656 elems per operator
  const size_t needFloats = (size_t)29*PP;              // dB0,dB1,pB0,pB1,part,ev2
  const size_t need16 = 2*S16E*sizeof(__half) + needFloats*sizeof(float);
  const bool f16 = (ws_size >= need16);

  __half* S16n = nullptr; __half* S16s = nullptr; float* fbase;
  if (f16){
    S16n = (__half*)d_ws;
    S16s = S16n + S16E;
    fbase = (float*)(S16s + S16E);
  } else {
    fbase = (float*)d_ws;
  }
  float* dB0  = fbase;            fbase += PP;
  float* dB1  = fbase;            fbase += PP;
  float* pB0  = fbase;            fbase += NPRIM*PP;
  float* pB1  = fbase;            fbase += NPRIM*PP;
  float* part = fbase;            fbase += 16*PP;
  float* ev2  = fbase;            fbase += PP;

  for (int k = 0; k < NITER; ++k){
    const float* dcur = (k == 0) ? dual   : ((k & 1) ? dB0 : dB1);
    float*       dnxt = (k & 1) ? dB1 : dB0;
    const float* pcur = (k == 0) ? primal : ((k & 1) ? pB0 : pB1);
    float*       pnxt = (k & 1) ? pB1 : pB0;
    float*       out2 = (k == NITER-1) ? (float*)d_out : nullptr;

    if (f16){
      if (k == 0) k_ev1<1><<<dim3(96,16), 256, 0, stream>>>(Snorm, S16n, pcur, part);
      else        k_ev1<2><<<dim3(96,16), 256, 0, stream>>>(nullptr, S16n, pcur, part);
    } else        k_ev1<0><<<dim3(96,16), 256, 0, stream>>>(Snorm, nullptr, pcur, part);

    k_conv_block<3,1,true><<<dim3(16,16), 256, 0, stream>>>(
        dcur, 1, part, 1, proj,
        dW1 + (size_t)k*32*3*9, db1 + (size_t)k*32, da1 + k,
        dW2 + (size_t)k*32*32*9, db2 + (size_t)k*32, da2 + k,
        dW3 + (size_t)k*1*32*9, db3 + (size_t)k*1, dnxt, nullptr);

    if (f16){
      if (k == 0) k_bp<1><<<576, 192, 0, stream>>>(S, S16s, dnxt, ev2);
      else        k_bp<2><<<576, 192, 0, stream>>>(nullptr, S16s, dnxt, ev2);
    } else        k_bp<0><<<576, 192, 0, stream>>>(S, nullptr, dnxt, ev2);

    k_conv_block<6,5,false><<<dim3(16,16), 256, 0, stream>>>(
        pcur, 5, ev2, 1, ev2,
        pW1 + (size_t)k*32*6*9, pb1 + (size_t)k*32, pa1 + k,
        pW2 + (size_t)k*32*32*9, pb2 + (size_t)k*32, pa2 + k,
        pW3 + (size_t)k*5*32*9, pb3 + (size_t)k*5, pnxt, out2);
  }
}

// Round 5
// 1121.380 us; speedup vs baseline: 1.5839x; 1.1262x over previous
//
#include <hip/hip_runtime.h>
#include <hip/hip_fp16.h>
#include <cstdint>
#include <cstddef>

#define PP 9216
#define NPRIM 5
#define NITER 10
#define IMG 9216

typedef float vf4 __attribute__((ext_vector_type(4)));
union H8 { vf4 f4; __half h[8]; };

// ---------------- ev1 partial: grid (96 a, 16 chunks), block 256 ----------------
// ev1[a,x] = sum_p Snorm[a,0,p,x] * img[p],  img[p] = primal[ch1][h,w], p = w*96+h
// MODE 0: pure fp32 (fallback). MODE 1: read fp32, round via fp16, write fp16 copy.
// MODE 2: read fp16 copy.
template<int MODE>
__global__ __launch_bounds__(256) void k_ev1(const float* __restrict__ Sf,
                                             __half* __restrict__ S16,
                                             const float* __restrict__ prim,
                                             float* __restrict__ part){
  const int a = blockIdx.x, c = blockIdx.y;
  const int p0 = c*576;
  const int tid = threadIdx.x;
  __shared__ float img[576];
  __shared__ float red[240][8];
  const float* prim1 = prim + IMG; // channel 1
  for (int idx = tid; idx < 576; idx += 256){
    int p = p0 + idx;
    int h = p % 96, w = p / 96;
    img[idx] = prim1[h*96 + w];
  }
  __syncthreads();
  if (tid < 240){
    const int xg = tid % 12, pr = tid / 12;   // xg: 12 x 8 halves = 96, pr: 0..19
    float acc[8];
    #pragma unroll
    for (int j = 0; j < 8; ++j) acc[j] = 0.f;
    const size_t base = ((size_t)a*PP + p0)*96 + 8*xg;
    #pragma unroll 2
    for (int pi = pr; pi < 576; pi += 20){
      float s[8];
      if (MODE == 2){
        H8 u; u.f4 = __builtin_nontemporal_load(reinterpret_cast<const vf4*>(S16 + base + (size_t)pi*96));
        #pragma unroll
        for (int j = 0; j < 8; ++j) s[j] = __half2float(u.h[j]);
      } else {
        const vf4 q0 = __builtin_nontemporal_load(reinterpret_cast<const vf4*>(Sf + base + (size_t)pi*96));
        const vf4 q1 = __builtin_nontemporal_load(reinterpret_cast<const vf4*>(Sf + base + (size_t)pi*96 + 4));
        float t[8] = {q0.x,q0.y,q0.z,q0.w,q1.x,q1.y,q1.z,q1.w};
        if (MODE == 1){
          H8 u;
          #pragma unroll
          for (int j = 0; j < 8; ++j){ u.h[j] = __float2half(t[j]); s[j] = __half2float(u.h[j]); }
          __builtin_nontemporal_store(u.f4, reinterpret_cast<vf4*>(S16 + base + (size_t)pi*96));
        } else {
          #pragma unroll
          for (int j = 0; j < 8; ++j) s[j] = t[j];
        }
      }
      const float im = img[pi];
      #pragma unroll
      for (int j = 0; j < 8; ++j) acc[j] += im*s[j];
    }
    #pragma unroll
    for (int j = 0; j < 8; ++j) red[tid][j] = acc[j];
  }
  __syncthreads();
  if (tid < 12){
    float r[8];
    #pragma unroll
    for (int j = 0; j < 8; ++j) r[j] = red[tid][j];
    for (int q = 1; q < 20; ++q)
      #pragma unroll
      for (int j = 0; j < 8; ++j) r[j] += red[tid + 12*q][j];
    float* dst = &part[((size_t)a*16 + c)*96 + 8*tid];
    vf4 v0 = {r[0],r[1],r[2],r[3]}, v1 = {r[4],r[5],r[6],r[7]};
    *reinterpret_cast<vf4*>(dst) = v0;
    *reinterpret_cast<vf4*>(dst+4) = v1;
  }
}

// ---------------- back projection: grid 576 (16 p-rows each), block 192 ----------------
// bp[p] = sum_{a,x} S[a,0,p,x]*dual[a,x]; ev2 image [h][w] = bp[w*96+h]
template<int MODE>
__global__ __launch_bounds__(192) void k_bp(const float* __restrict__ Sf,
                                            __half* __restrict__ S16,
                                            const float* __restrict__ dual,
                                            float* __restrict__ ev2){
  __shared__ float d2[PP];
  __shared__ float red[192];
  const int tid = threadIdx.x;
  for (int i = tid; i < PP/4; i += 192)
    reinterpret_cast<vf4*>(d2)[i] = reinterpret_cast<const vf4*>(dual)[i];
  __syncthreads();
  const int p0 = blockIdx.x * 16;
  const int xg = tid % 12, pr = tid / 12;   // xg: 12 x 8 halves = 96, pr: 0..15
  const int p = p0 + pr;
  float acc = 0.f;
  const size_t base = (size_t)p*96 + 8*xg;
  const size_t astr = (size_t)PP*96;
  #pragma unroll 4
  for (int a = 0; a < 96; ++a){
    float s[8];
    if (MODE == 2){
      H8 u; u.f4 = __builtin_nontemporal_load(reinterpret_cast<const vf4*>(S16 + base + (size_t)a*astr));
      #pragma unroll
      for (int j = 0; j < 8; ++j) s[j] = __half2float(u.h[j]);
    } else {
      const vf4 q0 = __builtin_nontemporal_load(reinterpret_cast<const vf4*>(Sf + base + (size_t)a*astr));
      const vf4 q1 = __builtin_nontemporal_load(reinterpret_cast<const vf4*>(Sf + base + (size_t)a*astr + 4));
      float t[8] = {q0.x,q0.y,q0.z,q0.w,q1.x,q1.y,q1.z,q1.w};
      if (MODE == 1){
        H8 u;
        #pragma unroll
        for (int j = 0; j < 8; ++j){ u.h[j] = __float2half(t[j]); s[j] = __half2float(u.h[j]); }
        __builtin_nontemporal_store(u.f4, reinterpret_cast<vf4*>(S16 + base + (size_t)a*astr));
      } else {
        #pragma unroll
        for (int j = 0; j < 8; ++j) s[j] = t[j];
      }
    }
    const vf4 da = *reinterpret_cast<const vf4*>(&d2[a*96 + 8*xg]);
    const vf4 db = *reinterpret_cast<const vf4*>(&d2[a*96 + 8*xg + 4]);
    acc += s[0]*da.x + s[1]*da.y + s[2]*da.z + s[3]*da.w
         + s[4]*db.x + s[5]*db.y + s[6]*db.z + s[7]*db.w;
  }
  red[tid] = acc;
  __syncthreads();
  if (tid < 16){
    float s = 0.f;
    #pragma unroll
    for (int j = 0; j < 12; ++j) s += red[tid*12 + j];
    int pp = p0 + tid;
    int h = pp % 96, w = pp / 96;
    ev2[h*96 + w] = s;
  }
}

// ---------------- fused conv1+PReLU+conv2+PReLU+conv3+residual block ----------------
// 6x6 output tile per block, grid 16x16, block 256. LDS phases overlaid to stay <64KB.
// Each conv layer zero-pads its OWN input ('SAME'): intermediate values at
// out-of-image positions are forced to ZERO.
// REDB: inB is the 16-chunk partial buffer; the loader sums the chunks (fused ev1 reduce).
// out2: if non-null, conv3 channel 0 is also written there (fused final extract).
template<int CIN, int COUT, bool REDB>
__global__ __launch_bounds__(256) void k_conv_block(
    const float* __restrict__ inA, int nA, const float* __restrict__ inB, int nB,
    const float* __restrict__ inC,
    const float* __restrict__ W1, const float* __restrict__ B1, const float* __restrict__ A1,
    const float* __restrict__ W2, const float* __restrict__ B2, const float* __restrict__ A2,
    const float* __restrict__ W3, const float* __restrict__ B3,
    float* __restrict__ out, float* __restrict__ out2)
{
  constexpr int C1F  = 32*10*12;   // conv1 out tile [32][10][12-padded]
  constexpr int C2F  = 32*8*9;     // conv2 out tile [32][8][9-padded]
  constexpr int XINF = CIN*144;    // input tile [CIN][12][12]
  constexpr int W1F  = 32*CIN*9;
  constexpr int W2F  = 288*32;     // w2 transposed [ci*9+k][och]
  constexpr int W3F  = COUT*32*9;
  constexpr int OV1  = (XINF+W1F > W2F) ? XINF+W1F : W2F;
  constexpr int OVLF = (OV1 > W3F) ? OV1 : W3F;

  __shared__ float c1s[C1F];
  __shared__ float c2s[C2F];
  __shared__ float bias1[32], bias2[32], bias3[COUT], alph[2];
  __shared__ float ovl[OVLF];

  const int tid = threadIdx.x;
  const int x0 = blockIdx.x * 6, y0 = blockIdx.y * 6;

  float* xin = ovl;            // [CIN][12][12]
  float* w1s = ovl + XINF;

  // ---- load input tile (zero-padded) + w1 + biases/alphas ----
  for (int i = tid; i < XINF; i += 256){
    int ch = i / 144, r = (i % 144) / 12, cc = i % 12;
    int gy = y0 - 3 + r, gx = x0 - 3 + cc;
    float v = 0.f;
    if (gy >= 0 && gy < 96 && gx >= 0 && gx < 96){
      if (REDB && ch >= nA && ch < nA + nB){
        float s = 0.f;
        #pragma unroll
        for (int cch = 0; cch < 16; ++cch) s += inB[((size_t)gy*16 + cch)*96 + gx];
        v = s;
      } else {
        const float* src = (ch < nA) ? (inA + (size_t)ch*IMG)
                         : (ch < nA+nB) ? (inB + (size_t)(ch-nA)*IMG)
                         : (inC + (size_t)(ch-nA-nB)*IMG);
        v = src[gy*96 + gx];
      }
    }
    xin[i] = v;
  }
  for (int i = tid; i < W1F; i += 256) w1s[i] = W1[i];
  if (tid < 32) bias1[tid] = B1[tid];
  else if (tid < 64) bias2[tid-32] = B2[tid-32];
  else if (tid < 64+COUT) bias3[tid-64] = B3[tid-64];
  else if (tid == 96) alph[0] = A1[0];
  else if (tid == 97) alph[1] = A2[0];
  __syncthreads();

  // ---- conv1 (CIN -> 32) + PReLU ----
  {
    const int och = tid & 31, t = tid >> 5;
    const float al = alph[0];
    for (int r = t; r < 10; r += 8){
      const int gy = y0 - 2 + r;
      float acc[10];
      #pragma unroll
      for (int cc = 0; cc < 10; ++cc) acc[cc] = bias1[och];
      #pragma unroll
      for (int ci = 0; ci < CIN; ++ci){
        float xr[3][12];
        #pragma unroll
        for (int ky = 0; ky < 3; ++ky){
          #pragma unroll
          for (int j = 0; j < 3; ++j){
            vf4 q = *reinterpret_cast<const vf4*>(&xin[ci*144 + (r+ky)*12 + 4*j]);
            xr[ky][4*j+0]=q.x; xr[ky][4*j+1]=q.y; xr[ky][4*j+2]=q.z; xr[ky][4*j+3]=q.w;
          }
        }
        float wv[9];
        #pragma unroll
        for (int kk = 0; kk < 9; ++kk) wv[kk] = w1s[(och*CIN+ci)*9 + kk];
        #pragma unroll
        for (int ky = 0; ky < 3; ++ky)
          #pragma unroll
          for (int kx = 0; kx < 3; ++kx)
            #pragma unroll
            for (int cc = 0; cc < 10; ++cc)
              acc[cc] += xr[ky][cc+kx] * wv[ky*3+kx];
      }
      const bool yin = (gy >= 0 && gy < 96);
      #pragma unroll
      for (int cc = 0; cc < 10; ++cc){
        const int gx = x0 - 2 + cc;
        float v = acc[cc];
        v = (v >= 0.f) ? v : al*v;
        const bool in = yin && (gx >= 0 && gx < 96);
        c1s[(och*10 + r)*12 + cc] = in ? v : 0.f;
      }
    }
  }
  // ---- pull residual into regs before xin is overlaid ----
  float resv = 0.f;
  {
    int sp = tid % 36, och = tid / 36;
    if (och < COUT){
      int ty = sp / 6, tx = sp % 6;
      resv = xin[och*144 + (ty+3)*12 + (tx+3)];
    }
  }
  // ---- coalesced W2 load into registers (before barrier overlays xin) ----
  // thread tid owns W2 elements [tid*36, tid*36+36): och = tid>>3, k0 = (tid&7)*36
  float w2r[36];
  {
    const vf4* src = reinterpret_cast<const vf4*>(W2 + (size_t)tid*36);
    #pragma unroll
    for (int q = 0; q < 9; ++q) reinterpret_cast<vf4*>(w2r)[q] = src[q];
  }
  __syncthreads();

  // ---- scatter W2 into overlay transposed: w2t[(ci*9+kk)*32 + och] ----
  float* w2t = ovl;
  {
    const int och = tid >> 3, k0 = (tid & 7)*36;
    #pragma unroll
    for (int j = 0; j < 36; ++j) w2t[(k0 + j)*32 + och] = w2r[j];
  }
  __syncthreads();

  // ---- conv2 (32 -> 32) + PReLU ----
  {
    const int och = tid & 31, ty = tid >> 5;  // ty 0..7
    const int gy = y0 - 1 + ty;
    const float al = alph[1];
    float acc[8];
    #pragma unroll
    for (int cc = 0; cc < 8; ++cc) acc[cc] = bias2[och];
    for (int ci = 0; ci < 32; ++ci){
      float cr[3][12];
      #pragma unroll
      for (int ky = 0; ky < 3; ++ky){
        #pragma unroll
        for (int j = 0; j < 3; ++j){
          vf4 q = *reinterpret_cast<const vf4*>(&c1s[(ci*10 + ty+ky)*12 + 4*j]);
          cr[ky][4*j+0]=q.x; cr[ky][4*j+1]=q.y; cr[ky][4*j+2]=q.z; cr[ky][4*j+3]=q.w;
        }
      }
      float wv[9];
      #pragma unroll
      for (int kk = 0; kk < 9; ++kk) wv[kk] = w2t[(ci*9+kk)*32 + och];
      #pragma unroll
      for (int ky = 0; ky < 3; ++ky)
        #pragma unroll
        for (int kx = 0; kx < 3; ++kx)
          #pragma unroll
          for (int cc = 0; cc < 8; ++cc)
            acc[cc] += cr[ky][cc+kx] * wv[ky*3+kx];
    }
    const bool yin = (gy >= 0 && gy < 96);
    #pragma unroll
    for (int cc = 0; cc < 8; ++cc){
      const int gx = x0 - 1 + cc;
      float v = acc[cc];
      v = (v >= 0.f) ? v : al*v;
      const bool in = yin && (gx >= 0 && gx < 96);
      c2s[(och*8 + ty)*9 + cc] = in ? v : 0.f;
    }
  }
  __syncthreads();

  // ---- load w3 into overlay ----
  float* w3s = ovl;
  for (int i = tid; i < W3F; i += 256) w3s[i] = W3[i];
  __syncthreads();

  // ---- conv3 (32 -> COUT) + bias + residual ----
  {
    int sp = tid % 36, och = tid / 36;
    if (och < COUT){
      int ty = sp / 6, tx = sp % 6;
      float acc = bias3[och];
      for (int ci = 0; ci < 32; ++ci){
        #pragma unroll
        for (int ky = 0; ky < 3; ++ky)
          #pragma unroll
          for (int kx = 0; kx < 3; ++kx)
            acc += c2s[(ci*8 + ty+ky)*9 + (tx+kx)] * w3s[(och*32+ci)*9 + ky*3+kx];
      }
      const float vout = resv + acc;
      const int idx = (y0+ty)*96 + (x0+tx);
      out[(size_t)och*IMG + idx] = vout;
      if (out2 != nullptr && och == 0) out2[idx] = vout;
    }
  }
}

extern "C" void kernel_launch(void* const* d_in, const int* in_sizes, int n_in,
                              void* d_out, int out_size, void* d_ws, size_t ws_size,
                              hipStream_t stream){
  (void)in_sizes; (void)n_in; (void)out_size;
  const float* dual   = (const float*)d_in[0];
  const float* primal = (const float*)d_in[1];
  const float* proj   = (const float*)d_in[2];
  const float* S      = (const float*)d_in[3];
  const float* Snorm  = (const float*)d_in[4];
  const float* dW1 = (const float*)d_in[5];
  const float* db1 = (const float*)d_in[6];
  const float* da1 = (const float*)d_in[7];
  const float* dW2 = (const float*)d_in[8];
  const float* db2 = (const float*)d_in[9];
  const float* da2 = (const float*)d_in[10];
  const float* dW3 = (const float*)d_in[11];
  const float* db3 = (const float*)d_in[12];
  const float* pW1 = (const float*)d_in[13];
  const float* pb1 = (const float*)d_in[14];
  const float* pa1 = (const float*)d_in[15];
  const float* pW2 = (const float*)d_in[16];
  const float* pb2 = (const float*)d_in[17];
  const float* pa2 = (const float*)d_in[18];
  const float* pW3 = (const float*)d_in[19];
  const float* pb3 = (const float*)d_in[20];

  const size_t S16E = (size_t)96*PP*96;                 // 84,934,656 elems per operator
  const size_t needFloats = (size_t)29*PP;              // dB0,dB1,pB0,pB1,part,ev2
  const size_t need16 = 2*S16E*sizeof(__half) + needFloats*sizeof(float);
  const bool f16 = (ws_size >= need16);

  __half* S16n = nullptr; __half* S16s = nullptr; float* fbase;
  if (f16){
    S16n = (__half*)d_ws;
    S16s = S16n + S16E;
    fbase = (float*)(S16s + S16E);
  } else {
    fbase = (float*)d_ws;
  }
  float* dB0  = fbase;            fbase += PP;
  float* dB1  = fbase;            fbase += PP;
  float* pB0  = fbase;            fbase += NPRIM*PP;
  float* pB1  = fbase;            fbase += NPRIM*PP;
  float* part = fbase;            fbase += 16*PP;
  float* ev2  = fbase;            fbase += PP;

  for (int k = 0; k < NITER; ++k){
    const float* dcur = (k == 0) ? dual   : ((k & 1) ? dB0 : dB1);
    float*       dnxt = (k & 1) ? dB1 : dB0;
    const float* pcur = (k == 0) ? primal : ((k & 1) ? pB0 : pB1);
    float*       pnxt = (k & 1) ? pB1 : pB0;
    float*       out2 = (k == NITER-1) ? (float*)d_out : nullptr;

    if (f16){
      if (k == 0) k_ev1<1><<<dim3(96,16), 256, 0, stream>>>(Snorm, S16n, pcur, part);
      else        k_ev1<2><<<dim3(96,16), 256, 0, stream>>>(nullptr, S16n, pcur, part);
    } else        k_ev1<0><<<dim3(96,16), 256, 0, stream>>>(Snorm, nullptr, pcur, part);

    k_conv_block<3,1,true><<<dim3(16,16), 256, 0, stream>>>(
        dcur, 1, part, 1, proj,
        dW1 + (size_t)k*32*3*9, db1 + (size_t)k*32, da1 + k,
        dW2 + (size_t)k*32*32*9, db2 + (size_t)k*32, da2 + k,
        dW3 + (size_t)k*1*32*9, db3 + (size_t)k*1, dnxt, nullptr);

    if (f16){
      if (k == 0) k_bp<1><<<576, 192, 0, stream>>>(S, S16s, dnxt, ev2);
      else        k_bp<2><<<576, 192, 0, stream>>>(nullptr, S16s, dnxt, ev2);
    } else        k_bp<0><<<576, 192, 0, stream>>>(S, nullptr, dnxt, ev2);

    k_conv_block<6,5,false><<<dim3(16,16), 256, 0, stream>>>(
        pcur, 5, ev2, 1, ev2,
        pW1 + (size_t)k*32*6*9, pb1 + (size_t)k*32, pa1 + k,
        pW2 + (size_t)k*32*32*9, pb2 + (size_t)k*32, pa2 + k,
        pW3 + (size_t)k*5*32*9, pb3 + (size_t)k*5, pnxt, out2);
  }
}